// Round 12
// baseline (324.703 us; speedup 1.0000x reference)
//
#include <hip/hip_runtime.h>
#include <cstddef>
#include <cstdint>

#define NE 2048
#define NX 3
#define NROWS (NE - 1)               // rows solved: i = 0..2046
#define BS 64                        // block size (rows per block)
#define BR (3 * BS)                  // 192
#define NBLK 32
#define NPAIR 16
#define NCH 8                        // K-staging chunks in k_tinv
#define CHS 8                        // steps per chunk
#define CHQ (CHS * 9 * BS)           // 4608 floats per chunk
#define TTH 512                      // k_tinv threads
#define PERTH (CHQ / TTH)            // 9 floats per thread

// PLANAR index convention for all 192-vectors/operators: idx = species*64 + energy.
// ws layout (floats):
//   wf   [3*NE]            @ 0
//   acc  [3*NE]            @ 3*NE
//   G    [32*BR*BR]        @ 6*NE            T^{-1} per block (planar, row-major)
//   ops1 [32][3][BR*BR]    @ after G         H (t=1), J2 (t=2), J3 (t=3)
//   pr   [16][3][BR*BR]    @ after ops1      P, R2, R3 per pair

static __device__ __forceinline__ float dy_of(const float* E) {
    return logf(E[NE - 1] / E[0]) / (float)(NE - 1);
}

__global__ void k_init(const float* __restrict__ E, const float* __restrict__ R,
                       const float* __restrict__ K, const float* __restrict__ S0,
                       const float* __restrict__ SC,
                       float* __restrict__ out, float* __restrict__ wf,
                       float* __restrict__ acc) {
    int i = blockIdx.x * blockDim.x + threadIdx.x;
    if (i >= NE) return;
    const size_t PL = (size_t)NE * NE;
    float dy = dy_of(E);
    float wlast = 0.5f * dy * E[NE - 1];
    float srcl[NX], Fl[NX];
#pragma unroll
    for (int p = 0; p < NX; ++p) srcl[p] = S0[p] / R[p * NE + NE - 1];
#pragma unroll
    for (int x = 0; x < NX; ++x) {
        float s = SC[x * NE + NE - 1];
#pragma unroll
        for (int p = 0; p < NX; ++p)
            s += K[(size_t)(x * NX + p) * PL + (size_t)(NE - 1) * NE + (NE - 1)] * srcl[p];
        Fl[x] = s / R[x * NE + NE - 1];
    }
    out[i] = E[i];
    if (i == NE - 1) {
#pragma unroll
        for (int x = 0; x < NX; ++x) {
            out[(1 + x) * NE + i] = Fl[x] > 0.f ? Fl[x] : 0.f;
            wf[x * NE + i] = wlast * Fl[x];
            acc[x * NE + i] = 0.f;
        }
        return;
    }
#pragma unroll
    for (int x = 0; x < NX; ++x) {
        float s = SC[x * NE + i];
#pragma unroll
        for (int p = 0; p < NX; ++p)
            s += K[(size_t)(x * NX + p) * PL + (size_t)i * NE + (NE - 1)] *
                 (wlast * Fl[p] + srcl[p]);
        acc[x * NE + i] = s;
    }
}

// Per-block inverse (R7-proven compute; dump remapped to PLANAR).
__global__ __launch_bounds__(TTH) void k_tinv(const float* __restrict__ E,
                                              const float* __restrict__ R,
                                              const float* __restrict__ K,
                                              float* __restrict__ G) {
    __shared__ float4 Xs4[BS][BS + 1];
    __shared__ float Kst[CHS][BS][12];
    __shared__ float Binv[BS][9];
    __shared__ float wloc[BS];
    const size_t PL = (size_t)NE * NE;
    int b = blockIdx.x;
    int g = blockIdx.y;
    int i0 = b * BS;
    int tid = threadIdx.x;
    float dy = dy_of(E);

    if (tid < BS) {
        int j = i0 + tid;
        wloc[tid] = (j < NE - 1) ? dy * E[j] : 0.f;
        int ii = tid, i = i0 + ii;
        float b00, b01, b02, b10, b11, b12, b20, b21, b22;
        if (i < NROWS) {
            float h = -0.5f * dy * E[i];
            size_t d = (size_t)i * NE + i;
            b00 = h * K[0 * PL + d] + R[0 * NE + i];
            b01 = h * K[1 * PL + d];
            b02 = h * K[2 * PL + d];
            b10 = h * K[3 * PL + d];
            b11 = h * K[4 * PL + d] + R[1 * NE + i];
            b12 = h * K[5 * PL + d];
            b20 = h * K[6 * PL + d];
            b21 = h * K[7 * PL + d];
            b22 = h * K[8 * PL + d] + R[2 * NE + i];
        } else {
            b00 = 1.f; b01 = 0.f; b02 = 0.f;
            b10 = 0.f; b11 = 1.f; b12 = 0.f;
            b20 = 0.f; b21 = 0.f; b22 = 1.f;
        }
        float C00 = b11 * b22 - b12 * b21;
        float C01 = -(b10 * b22 - b12 * b20);
        float C02 = b10 * b21 - b11 * b20;
        float C10 = -(b01 * b22 - b02 * b21);
        float C11 = b00 * b22 - b02 * b20;
        float C12 = -(b00 * b21 - b01 * b20);
        float C20 = b01 * b12 - b02 * b11;
        float C21 = -(b00 * b12 - b02 * b10);
        float C22 = b00 * b11 - b01 * b10;
        float inv = 1.f / (b00 * C00 + b01 * C01 + b02 * C02);
        Binv[ii][0] = C00 * inv; Binv[ii][1] = C10 * inv; Binv[ii][2] = C20 * inv;
        Binv[ii][3] = C01 * inv; Binv[ii][4] = C11 * inv; Binv[ii][5] = C21 * inv;
        Binv[ii][6] = C02 * inv; Binv[ii][7] = C12 * inv; Binv[ii][8] = C22 * inv;
    }
    __syncthreads();

    float rg[PERTH];
#pragma unroll
    for (int k = 0; k < PERTH; ++k) {
        int q = tid + k * TTH;
        int s = q / (9 * BS);
        int pair = (q / BS) % 9;
        int jj = q & (BS - 1);
        int row = i0 + (BS - 1) - s;
        rg[k] = K[(size_t)pair * PL + (size_t)row * NE + (i0 + jj)];
    }

    int cloc = tid >> 3, sub = tid & 7;
    int colb = g * BS + cloc;

    for (int c = 0; c < NCH; ++c) {
        if (c > 0) __syncthreads();
#pragma unroll
        for (int k = 0; k < PERTH; ++k) {
            int q = tid + k * TTH;
            int s = q / (9 * BS);
            int pair = (q / BS) % 9;
            int jj = q & (BS - 1);
            Kst[s][jj][4 * (pair / 3) + (pair % 3)] = rg[k] * wloc[jj];
        }
        __syncthreads();
        if (c + 1 < NCH) {
#pragma unroll
            for (int k = 0; k < PERTH; ++k) {
                int q = tid + k * TTH;
                int s = q / (9 * BS);
                int pair = (q / BS) % 9;
                int jj = q & (BS - 1);
                int row = i0 + (BS - 1) - ((c + 1) * CHS + s);
                rg[k] = K[(size_t)pair * PL + (size_t)row * NE + (i0 + jj)];
            }
        }
        for (int s = 0; s < CHS; ++s) {
            int ii = (BS - 1) - (c * CHS + s);
            int i = i0 + ii;
            float v0 = 0.f, v1 = 0.f, v2 = 0.f;
            if (sub == 0) {
                v0 = (colb == 3 * ii + 0) ? 1.f : 0.f;
                v1 = (colb == 3 * ii + 1) ? 1.f : 0.f;
                v2 = (colb == 3 * ii + 2) ? 1.f : 0.f;
            }
            if (i < NROWS) {
                for (int jj = ii + 1 + sub; jj < BS; jj += 8) {
                    const float* kp = &Kst[s][jj][0];
                    float4 k0 = *(const float4*)(kp);
                    float4 k1 = *(const float4*)(kp + 4);
                    float4 k2 = *(const float4*)(kp + 8);
                    float4 xv = Xs4[jj][cloc];
                    v0 += k0.x * xv.x + k0.y * xv.y + k0.z * xv.z;
                    v1 += k1.x * xv.x + k1.y * xv.y + k1.z * xv.z;
                    v2 += k2.x * xv.x + k2.y * xv.y + k2.z * xv.z;
                }
            }
            v0 += __shfl_xor(v0, 1); v0 += __shfl_xor(v0, 2); v0 += __shfl_xor(v0, 4);
            v1 += __shfl_xor(v1, 1); v1 += __shfl_xor(v1, 2); v1 += __shfl_xor(v1, 4);
            v2 += __shfl_xor(v2, 1); v2 += __shfl_xor(v2, 2); v2 += __shfl_xor(v2, 4);
            if (sub == 0) {
                float f0, f1, f2;
                if (i < NROWS) {
                    const float* bv = Binv[ii];
                    f0 = bv[0] * v0 + bv[1] * v1 + bv[2] * v2;
                    f1 = bv[3] * v0 + bv[4] * v1 + bv[5] * v2;
                    f2 = bv[6] * v0 + bv[7] * v1 + bv[8] * v2;
                } else {
                    f0 = v0; f1 = v1; f2 = v2;
                }
                Xs4[ii][cloc] = make_float4(f0, f1, f2, 0.f);
            }
            __builtin_amdgcn_wave_barrier();
        }
    }
    __syncthreads();
    // PLANAR dump: X[interleaved row 3ii+x][interleaved col colb=3jjc+pc]
    //  -> G[b][x*64+ii][pc*64+jjc]
    float* Gb = G + (size_t)b * BR * BR;
    for (int t = tid; t < BS * BR; t += TTH) {
        int cl = t % BS;                 // local col within group g
        int rp = t / BS;                 // planar row = x*64+ii
        int x = rp >> 6, ii = rp & 63;
        int cb = g * BS + cl;
        int jjc = cb / 3, pc = cb % 3;
        Gb[(size_t)rp * BR + (pc * 64 + jjc)] = ((const float*)&Xs4[ii][cl])[x];
    }
}

#define DOT4(a, b) ((a).x * (b).x + (a).y * (b).y + (a).z * (b).z + (a).w * (b).w)

// ops1[s][t-1] = G[s] @ Kp(s,s+t), planar. Kp[k=x*64+ii][c=p*64+jj] =
// K[x][p][s*64+ii][(s+t)*64+jj] (0 where col>=NROWS). grid (32, 3, 9=rt*3+ct).
// Tile rt = output-row species x-block isn't special; rt/ct are 64-chunks.
__global__ __launch_bounds__(256) void k_gops1(const float* __restrict__ K,
                                               const float* __restrict__ G,
                                               float* __restrict__ ops1) {
    int s = blockIdx.x, ty_ = blockIdx.y, tz = blockIdx.z;
    int rt = tz / 3, ct = tz % 3;
    int t = ty_ + 1;
    float* O = ops1 + (size_t)(s * 3 + ty_) * BR * BR;
    int tid = threadIdx.x;
    if (s + t > NBLK - 1) {
        for (int q = tid; q < 64 * 64; q += 256)
            O[(size_t)(rt * 64 + q / 64) * BR + ct * 64 + (q % 64)] = 0.f;
        return;
    }
    __shared__ float As[64][196];
    __shared__ float Bt[64][196];
    const size_t PL = (size_t)NE * NE;
    const float* Ga = G + (size_t)s * BR * BR;
    for (int q = tid; q < 64 * BR; q += 256) {
        int r = q / BR, k = q % BR;
        As[r][k] = Ga[(size_t)(rt * 64 + r) * BR + k];
    }
    int tgt0 = (s + t) * 64;
    for (int q = tid; q < BR * 64; q += 256) {
        int k = q >> 6, c = q & 63;        // c == jj (tile ct == species p)
        int x = k >> 6, ii = k & 63;
        int j = tgt0 + c;
        Bt[c][k] = (j < NROWS)
            ? K[(size_t)(x * 3 + ct) * PL + (size_t)(s * 64 + ii) * NE + j] : 0.f;
    }
    __syncthreads();
    int tx = tid & 15, ty = tid >> 4;
    float av[4][4] = {};
    for (int k = 0; k < BR; k += 4) {
        float4 a0 = *(const float4*)&As[ty * 4 + 0][k];
        float4 a1 = *(const float4*)&As[ty * 4 + 1][k];
        float4 a2 = *(const float4*)&As[ty * 4 + 2][k];
        float4 a3 = *(const float4*)&As[ty * 4 + 3][k];
        float4 b0 = *(const float4*)&Bt[tx * 4 + 0][k];
        float4 b1 = *(const float4*)&Bt[tx * 4 + 1][k];
        float4 b2 = *(const float4*)&Bt[tx * 4 + 2][k];
        float4 b3 = *(const float4*)&Bt[tx * 4 + 3][k];
        av[0][0] += DOT4(a0, b0); av[0][1] += DOT4(a0, b1);
        av[0][2] += DOT4(a0, b2); av[0][3] += DOT4(a0, b3);
        av[1][0] += DOT4(a1, b0); av[1][1] += DOT4(a1, b1);
        av[1][2] += DOT4(a1, b2); av[1][3] += DOT4(a1, b3);
        av[2][0] += DOT4(a2, b0); av[2][1] += DOT4(a2, b1);
        av[2][2] += DOT4(a2, b2); av[2][3] += DOT4(a2, b3);
        av[3][0] += DOT4(a3, b0); av[3][1] += DOT4(a3, b1);
        av[3][2] += DOT4(a3, b2); av[3][3] += DOT4(a3, b3);
    }
#pragma unroll
    for (int i = 0; i < 4; ++i)
#pragma unroll
        for (int j = 0; j < 4; ++j)
            O[(size_t)(rt * 64 + ty * 4 + i) * BR + ct * 64 + tx * 4 + j] = av[i][j];
}

// pr[m][w]: w=0: P = HwA@G_C; w=1: R2 = HwA@H_C + J2_A; w=2: R3 = HwA@J2_C + J3_A.
// HwA = H_A with col k scaled by w(C*64 + (k&63)) (planar). grid (16, 3, 9).
__global__ __launch_bounds__(256) void k_gops2(const float* __restrict__ E,
                                               const float* __restrict__ G,
                                               const float* __restrict__ ops1,
                                               float* __restrict__ pr) {
    int m = blockIdx.x, w = blockIdx.y, tz = blockIdx.z;
    int rt = tz / 3, ct = tz % 3;
    int A = 2 * m, C = 2 * m + 1;
    int tid = threadIdx.x;
    __shared__ float As[64][196];
    __shared__ float Bt[64][196];
    float dy = dy_of(E);
    const float* Asrc = ops1 + (size_t)(A * 3 + 0) * BR * BR;
    const float* Bsrc = (w == 0) ? (G + (size_t)C * BR * BR)
                                 : (ops1 + (size_t)(C * 3 + (w - 1)) * BR * BR);
    const float* Dsrc = (w == 0) ? nullptr
                                 : (ops1 + (size_t)(A * 3 + w) * BR * BR);
    float* O = pr + (size_t)(m * 3 + w) * BR * BR;
    for (int q = tid; q < 64 * BR; q += 256) {
        int r = q / BR, k = q % BR;
        int j = C * 64 + (k & 63);
        float wk = (j < NROWS) ? dy * E[j] : 0.f;
        As[r][k] = Asrc[(size_t)(rt * 64 + r) * BR + k] * wk;
    }
    for (int q = tid; q < BR * 64; q += 256) {
        int k = q >> 6, c = q & 63;
        Bt[c][k] = Bsrc[(size_t)k * BR + ct * 64 + c];
    }
    __syncthreads();
    int tx = tid & 15, ty = tid >> 4;
    float av[4][4] = {};
    for (int k = 0; k < BR; k += 4) {
        float4 a0 = *(const float4*)&As[ty * 4 + 0][k];
        float4 a1 = *(const float4*)&As[ty * 4 + 1][k];
        float4 a2 = *(const float4*)&As[ty * 4 + 2][k];
        float4 a3 = *(const float4*)&As[ty * 4 + 3][k];
        float4 b0 = *(const float4*)&Bt[tx * 4 + 0][k];
        float4 b1 = *(const float4*)&Bt[tx * 4 + 1][k];
        float4 b2 = *(const float4*)&Bt[tx * 4 + 2][k];
        float4 b3 = *(const float4*)&Bt[tx * 4 + 3][k];
        av[0][0] += DOT4(a0, b0); av[0][1] += DOT4(a0, b1);
        av[0][2] += DOT4(a0, b2); av[0][3] += DOT4(a0, b3);
        av[1][0] += DOT4(a1, b0); av[1][1] += DOT4(a1, b1);
        av[1][2] += DOT4(a1, b2); av[1][3] += DOT4(a1, b3);
        av[2][0] += DOT4(a2, b0); av[2][1] += DOT4(a2, b1);
        av[2][2] += DOT4(a2, b2); av[2][3] += DOT4(a2, b3);
        av[3][0] += DOT4(a3, b0); av[3][1] += DOT4(a3, b1);
        av[3][2] += DOT4(a3, b2); av[3][3] += DOT4(a3, b3);
    }
#pragma unroll
    for (int i = 0; i < 4; ++i)
#pragma unroll
        for (int j = 0; j < 4; ++j) {
            size_t o = (size_t)(rt * 64 + ty * 4 + i) * BR + ct * 64 + tx * 4 + j;
            O[o] = av[i][j] + (Dsrc ? Dsrc[o] : 0.f);
        }
}

// Pair stage (no intra-kernel deps):
//   bid 0..5 : F_C rows = G_C aC + H_C v2 + J2_C v3
//   bid 6..11: F_A rows = G_A aA + P aC + R2 v2 + R3 v3
//   bid >=12 : far — cols blocks 2m+2,2m+3 -> rows < 2m*64
__global__ __launch_bounds__(512) void k_pair2(const float* __restrict__ E,
                                               const float* __restrict__ K,
                                               const float* __restrict__ G,
                                               const float* __restrict__ ops1,
                                               const float* __restrict__ pr,
                                               float* __restrict__ acc,
                                               float* __restrict__ wf,
                                               float* __restrict__ out,
                                               int m, int hasV) {
    const size_t PL = (size_t)NE * NE;
    int A = 2 * m, C = 2 * m + 1;
    int tid = threadIdx.x;
    int bid = blockIdx.x;
    int lane = tid & 63, wv = tid >> 6;

    if (bid >= 12) {
        int jbase = (2 * m + 2) * BS;
        int row = (bid - 12) * 8 + wv;
        int j1 = jbase + lane, j2 = j1 + BS;
        float w10 = wf[0 * NE + j1], w11 = wf[1 * NE + j1], w12 = wf[2 * NE + j1];
        float w20 = 0.f, w21 = 0.f, w22 = 0.f;
        if (j2 < NROWS) {
            w20 = wf[0 * NE + j2]; w21 = wf[1 * NE + j2]; w22 = wf[2 * NE + j2];
        }
        const float* Kb1 = K + (size_t)row * NE + j1;
        const float* Kb2 = K + (size_t)row * NE + j2;
        float s0 = Kb1[0 * PL] * w10 + Kb1[1 * PL] * w11 + Kb1[2 * PL] * w12
                 + Kb2[0 * PL] * w20 + Kb2[1 * PL] * w21 + Kb2[2 * PL] * w22;
        float s1 = Kb1[3 * PL] * w10 + Kb1[4 * PL] * w11 + Kb1[5 * PL] * w12
                 + Kb2[3 * PL] * w20 + Kb2[4 * PL] * w21 + Kb2[5 * PL] * w22;
        float s2 = Kb1[6 * PL] * w10 + Kb1[7 * PL] * w11 + Kb1[8 * PL] * w12
                 + Kb2[6 * PL] * w20 + Kb2[7 * PL] * w21 + Kb2[8 * PL] * w22;
#pragma unroll
        for (int d = 32; d; d >>= 1) {
            s0 += __shfl_xor(s0, d);
            s1 += __shfl_xor(s1, d);
            s2 += __shfl_xor(s2, d);
        }
        if (lane == 0) {
            atomicAdd(&acc[0 * NE + row], s0);
            atomicAdd(&acc[1 * NE + row], s1);
            atomicAdd(&acc[2 * NE + row], s2);
        }
        return;
    }

    // ---- apply (planar vectors: idx = species*64 + energy) ----
    __shared__ float4 vec4[4][BR / 4];        // aC, aA, v2, v3
    float dy = dy_of(E);
    if (tid < BR) {
        int sp = tid >> 6, e = tid & 63;
        ((float*)vec4[0])[tid] = __hip_atomic_load(&acc[sp * NE + C * BS + e],
                                     __ATOMIC_RELAXED, __HIP_MEMORY_SCOPE_AGENT);
        ((float*)vec4[1])[tid] = __hip_atomic_load(&acc[sp * NE + A * BS + e],
                                     __ATOMIC_RELAXED, __HIP_MEMORY_SCOPE_AGENT);
        ((float*)vec4[2])[tid] = hasV ? wf[sp * NE + (2 * m + 2) * BS + e] : 0.f;
        ((float*)vec4[3])[tid] = hasV ? wf[sp * NE + (2 * m + 3) * BS + e] : 0.f;
    }
    __syncthreads();

    int rloc = tid >> 4, sub = tid & 15;      // 32 rows x 16 threads
    bool isC = (bid < 6);
    int rbase = (isC ? bid : bid - 6) * 32;
    int row = rbase + rloc;                   // planar row in [0,192)
    int blk = isC ? C : A;

    const float4* m0 = (const float4*)(G + ((size_t)blk * BR + row) * BR) + sub * 3;
    const float4 *m1, *m2, *m3 = nullptr;
    const float4 *x0, *x1, *x2, *x3 = nullptr;
    if (isC) {
        m1 = (const float4*)(ops1 + ((size_t)(C * 3 + 0) * BR + row) * BR) + sub * 3;
        m2 = (const float4*)(ops1 + ((size_t)(C * 3 + 1) * BR + row) * BR) + sub * 3;
        x0 = vec4[0] + sub * 3; x1 = vec4[2] + sub * 3; x2 = vec4[3] + sub * 3;
    } else {
        m1 = (const float4*)(pr + ((size_t)(m * 3 + 0) * BR + row) * BR) + sub * 3;
        m2 = (const float4*)(pr + ((size_t)(m * 3 + 1) * BR + row) * BR) + sub * 3;
        m3 = (const float4*)(pr + ((size_t)(m * 3 + 2) * BR + row) * BR) + sub * 3;
        x0 = vec4[1] + sub * 3; x1 = vec4[0] + sub * 3;
        x2 = vec4[2] + sub * 3; x3 = vec4[3] + sub * 3;
    }
    float s = 0.f;
#pragma unroll
    for (int q = 0; q < 3; ++q) s += DOT4(m0[q], x0[q]);
    if (hasV || !isC) {
#pragma unroll
        for (int q = 0; q < 3; ++q) s += DOT4(m1[q], x1[q]);
    }
    if (hasV) {
#pragma unroll
        for (int q = 0; q < 3; ++q) s += DOT4(m2[q], x2[q]);
        if (!isC) {
#pragma unroll
            for (int q = 0; q < 3; ++q) s += DOT4(m3[q], x3[q]);
        }
    }
    s += __shfl_xor(s, 1); s += __shfl_xor(s, 2);
    s += __shfl_xor(s, 4); s += __shfl_xor(s, 8);
    if (sub == 0) {
        int x = row >> 6, ii = row & 63;
        int i = blk * BS + ii;
        if (i < NROWS) {
            out[(1 + x) * NE + i] = s > 0.f ? s : 0.f;
            wf[x * NE + i] = dy * E[i] * s;
        }
    }
}

extern "C" void kernel_launch(void* const* d_in, const int* in_sizes, int n_in,
                              void* d_out, int out_size, void* d_ws, size_t ws_size,
                              hipStream_t stream) {
    const float* E = (const float*)d_in[0];
    const float* R = (const float*)d_in[1];
    const float* K = (const float*)d_in[2];
    const float* S0 = (const float*)d_in[3];
    const float* SC = (const float*)d_in[4];
    float* out = (float*)d_out;
    float* wf = (float*)d_ws;
    float* acc = wf + NX * NE;
    float* G = acc + NX * NE;
    float* ops1 = G + (size_t)NBLK * BR * BR;
    float* pr = ops1 + (size_t)NBLK * 3 * BR * BR;

    k_init<<<(NE + 255) / 256, 256, 0, stream>>>(E, R, K, S0, SC, out, wf, acc);
    k_tinv<<<dim3(NBLK, 3), TTH, 0, stream>>>(E, R, K, G);
    k_gops1<<<dim3(NBLK, 3, 9), 256, 0, stream>>>(K, G, ops1);
    k_gops2<<<dim3(NPAIR, 3, 9), 256, 0, stream>>>(E, G, ops1, pr);

    for (int m = NPAIR - 1; m >= 0; --m) {
        int nFar = (m < NPAIR - 1) ? m * 16 : 0;
        int hasV = (m < NPAIR - 1) ? 1 : 0;
        k_pair2<<<12 + nFar, 512, 0, stream>>>(E, K, G, ops1, pr, acc, wf, out,
                                               m, hasV);
    }
}

// Round 13
// 243.911 us; speedup vs baseline: 1.3312x; 1.3312x over previous
//
#include <hip/hip_runtime.h>
#include <cstddef>
#include <cstdint>

#define NE 2048
#define NX 3
#define NROWS (NE - 1)               // rows solved: i = 0..2046
#define BS 64                        // block size (rows per block)
#define BR (3 * BS)                  // 192
#define NBLK 32
#define NPAIR 16
#define NCH 8                        // K-staging chunks in k_tinv
#define CHS 8                        // steps per chunk
#define CHQ (CHS * 9 * BS)           // 4608 floats per chunk
#define TTH 512                      // k_tinv threads
#define PERTH (CHQ / TTH)            // 9 floats per thread

// PLANAR index convention for all 192-vectors/operators: idx = species*64 + energy.
// ws layout (floats):
//   wf   [3*NE]            @ 0
//   acc  [3*NE]            @ 3*NE
//   G    [32*BR*BR]        @ 6*NE            T^{-1} per block (planar, row-major)
//   ops1 [32][3][BR*BR]    @ after G         H (t=1), J2 (t=2), J3 (t=3)
//   pr   [16][3][BR*BR]    @ after ops1      P, R2, R3 per pair

static __device__ __forceinline__ float dy_of(const float* E) {
    return logf(E[NE - 1] / E[0]) / (float)(NE - 1);
}

#define DOT4(a, b) ((a).x * (b).x + (a).y * (b).y + (a).z * (b).z + (a).w * (b).w)
#define FMA4(acc, s, b) { (acc).x += (s) * (b).x; (acc).y += (s) * (b).y; \
                          (acc).z += (s) * (b).z; (acc).w += (s) * (b).w; }

__global__ void k_init(const float* __restrict__ E, const float* __restrict__ R,
                       const float* __restrict__ K, const float* __restrict__ S0,
                       const float* __restrict__ SC,
                       float* __restrict__ out, float* __restrict__ wf,
                       float* __restrict__ acc) {
    int i = blockIdx.x * blockDim.x + threadIdx.x;
    if (i >= NE) return;
    const size_t PL = (size_t)NE * NE;
    float dy = dy_of(E);
    float wlast = 0.5f * dy * E[NE - 1];
    float srcl[NX], Fl[NX];
#pragma unroll
    for (int p = 0; p < NX; ++p) srcl[p] = S0[p] / R[p * NE + NE - 1];
#pragma unroll
    for (int x = 0; x < NX; ++x) {
        float s = SC[x * NE + NE - 1];
#pragma unroll
        for (int p = 0; p < NX; ++p)
            s += K[(size_t)(x * NX + p) * PL + (size_t)(NE - 1) * NE + (NE - 1)] * srcl[p];
        Fl[x] = s / R[x * NE + NE - 1];
    }
    out[i] = E[i];
    if (i == NE - 1) {
#pragma unroll
        for (int x = 0; x < NX; ++x) {
            out[(1 + x) * NE + i] = Fl[x] > 0.f ? Fl[x] : 0.f;
            wf[x * NE + i] = wlast * Fl[x];
            acc[x * NE + i] = 0.f;
        }
        return;
    }
#pragma unroll
    for (int x = 0; x < NX; ++x) {
        float s = SC[x * NE + i];
#pragma unroll
        for (int p = 0; p < NX; ++p)
            s += K[(size_t)(x * NX + p) * PL + (size_t)i * NE + (NE - 1)] *
                 (wlast * Fl[p] + srcl[p]);
        acc[x * NE + i] = s;
    }
}

// Per-block inverse (R7-proven compute; dump remapped to PLANAR).
__global__ __launch_bounds__(TTH) void k_tinv(const float* __restrict__ E,
                                              const float* __restrict__ R,
                                              const float* __restrict__ K,
                                              float* __restrict__ G) {
    __shared__ float4 Xs4[BS][BS + 1];
    __shared__ float Kst[CHS][BS][12];
    __shared__ float Binv[BS][9];
    __shared__ float wloc[BS];
    const size_t PL = (size_t)NE * NE;
    int b = blockIdx.x;
    int g = blockIdx.y;
    int i0 = b * BS;
    int tid = threadIdx.x;
    float dy = dy_of(E);

    if (tid < BS) {
        int j = i0 + tid;
        wloc[tid] = (j < NE - 1) ? dy * E[j] : 0.f;
        int ii = tid, i = i0 + ii;
        float b00, b01, b02, b10, b11, b12, b20, b21, b22;
        if (i < NROWS) {
            float h = -0.5f * dy * E[i];
            size_t d = (size_t)i * NE + i;
            b00 = h * K[0 * PL + d] + R[0 * NE + i];
            b01 = h * K[1 * PL + d];
            b02 = h * K[2 * PL + d];
            b10 = h * K[3 * PL + d];
            b11 = h * K[4 * PL + d] + R[1 * NE + i];
            b12 = h * K[5 * PL + d];
            b20 = h * K[6 * PL + d];
            b21 = h * K[7 * PL + d];
            b22 = h * K[8 * PL + d] + R[2 * NE + i];
        } else {
            b00 = 1.f; b01 = 0.f; b02 = 0.f;
            b10 = 0.f; b11 = 1.f; b12 = 0.f;
            b20 = 0.f; b21 = 0.f; b22 = 1.f;
        }
        float C00 = b11 * b22 - b12 * b21;
        float C01 = -(b10 * b22 - b12 * b20);
        float C02 = b10 * b21 - b11 * b20;
        float C10 = -(b01 * b22 - b02 * b21);
        float C11 = b00 * b22 - b02 * b20;
        float C12 = -(b00 * b21 - b01 * b20);
        float C20 = b01 * b12 - b02 * b11;
        float C21 = -(b00 * b12 - b02 * b10);
        float C22 = b00 * b11 - b01 * b10;
        float inv = 1.f / (b00 * C00 + b01 * C01 + b02 * C02);
        Binv[ii][0] = C00 * inv; Binv[ii][1] = C10 * inv; Binv[ii][2] = C20 * inv;
        Binv[ii][3] = C01 * inv; Binv[ii][4] = C11 * inv; Binv[ii][5] = C21 * inv;
        Binv[ii][6] = C02 * inv; Binv[ii][7] = C12 * inv; Binv[ii][8] = C22 * inv;
    }
    __syncthreads();

    float rg[PERTH];
#pragma unroll
    for (int k = 0; k < PERTH; ++k) {
        int q = tid + k * TTH;
        int s = q / (9 * BS);
        int pair = (q / BS) % 9;
        int jj = q & (BS - 1);
        int row = i0 + (BS - 1) - s;
        rg[k] = K[(size_t)pair * PL + (size_t)row * NE + (i0 + jj)];
    }

    int cloc = tid >> 3, sub = tid & 7;
    int colb = g * BS + cloc;

    for (int c = 0; c < NCH; ++c) {
        if (c > 0) __syncthreads();
#pragma unroll
        for (int k = 0; k < PERTH; ++k) {
            int q = tid + k * TTH;
            int s = q / (9 * BS);
            int pair = (q / BS) % 9;
            int jj = q & (BS - 1);
            Kst[s][jj][4 * (pair / 3) + (pair % 3)] = rg[k] * wloc[jj];
        }
        __syncthreads();
        if (c + 1 < NCH) {
#pragma unroll
            for (int k = 0; k < PERTH; ++k) {
                int q = tid + k * TTH;
                int s = q / (9 * BS);
                int pair = (q / BS) % 9;
                int jj = q & (BS - 1);
                int row = i0 + (BS - 1) - ((c + 1) * CHS + s);
                rg[k] = K[(size_t)pair * PL + (size_t)row * NE + (i0 + jj)];
            }
        }
        for (int s = 0; s < CHS; ++s) {
            int ii = (BS - 1) - (c * CHS + s);
            int i = i0 + ii;
            float v0 = 0.f, v1 = 0.f, v2 = 0.f;
            if (sub == 0) {
                v0 = (colb == 3 * ii + 0) ? 1.f : 0.f;
                v1 = (colb == 3 * ii + 1) ? 1.f : 0.f;
                v2 = (colb == 3 * ii + 2) ? 1.f : 0.f;
            }
            if (i < NROWS) {
                for (int jj = ii + 1 + sub; jj < BS; jj += 8) {
                    const float* kp = &Kst[s][jj][0];
                    float4 k0 = *(const float4*)(kp);
                    float4 k1 = *(const float4*)(kp + 4);
                    float4 k2 = *(const float4*)(kp + 8);
                    float4 xv = Xs4[jj][cloc];
                    v0 += k0.x * xv.x + k0.y * xv.y + k0.z * xv.z;
                    v1 += k1.x * xv.x + k1.y * xv.y + k1.z * xv.z;
                    v2 += k2.x * xv.x + k2.y * xv.y + k2.z * xv.z;
                }
            }
            v0 += __shfl_xor(v0, 1); v0 += __shfl_xor(v0, 2); v0 += __shfl_xor(v0, 4);
            v1 += __shfl_xor(v1, 1); v1 += __shfl_xor(v1, 2); v1 += __shfl_xor(v1, 4);
            v2 += __shfl_xor(v2, 1); v2 += __shfl_xor(v2, 2); v2 += __shfl_xor(v2, 4);
            if (sub == 0) {
                float f0, f1, f2;
                if (i < NROWS) {
                    const float* bv = Binv[ii];
                    f0 = bv[0] * v0 + bv[1] * v1 + bv[2] * v2;
                    f1 = bv[3] * v0 + bv[4] * v1 + bv[5] * v2;
                    f2 = bv[6] * v0 + bv[7] * v1 + bv[8] * v2;
                } else {
                    f0 = v0; f1 = v1; f2 = v2;
                }
                Xs4[ii][cloc] = make_float4(f0, f1, f2, 0.f);
            }
            __builtin_amdgcn_wave_barrier();
        }
    }
    __syncthreads();
    // PLANAR dump: interleaved row 3ii+x, col 3jjc+pc -> G[b][x*64+ii][pc*64+jjc]
    float* Gb = G + (size_t)b * BR * BR;
    for (int t = tid; t < BS * BR; t += TTH) {
        int cl = t % BS;
        int rp = t / BS;
        int x = rp >> 6, ii = rp & 63;
        int cb = g * BS + cl;
        int jjc = cb / 3, pc = cb % 3;
        Gb[(size_t)rp * BR + (pc * 64 + jjc)] = ((const float*)&Xs4[ii][cl])[x];
    }
}

// ops1[s][t-1] = G[s] @ Kp(s,s+t), planar, LDS-FREE register-tiled GEMM.
// B read directly from K through L1: B[k=x*64+ii][c=jj] = K[x][ct][s64+ii][tgt0+jj].
// grid (32, 3, 9=rt*3+ct), 256 thr, each 4x4 outputs.
__global__ __launch_bounds__(256) void k_gops1(const float* __restrict__ K,
                                               const float* __restrict__ G,
                                               float* __restrict__ ops1) {
    int s = blockIdx.x, ty_ = blockIdx.y, tz = blockIdx.z;
    int rt = tz / 3, ct = tz % 3;
    int t = ty_ + 1;
    float* O = ops1 + (size_t)(s * 3 + ty_) * BR * BR;
    int tid = threadIdx.x;
    if (s + t > NBLK - 1) {
        for (int q = tid; q < 64 * 64; q += 256)
            O[(size_t)(rt * 64 + q / 64) * BR + ct * 64 + (q % 64)] = 0.f;
        return;
    }
    const size_t PL = (size_t)NE * NE;
    const float* Ga = G + (size_t)s * BR * BR;
    int tgt0 = (s + t) * 64;
    int tx = tid & 15, ty = tid >> 4;
    int row0 = rt * 64 + ty * 4;
    int c0 = tx * 4;
    bool maskLast = (s + t == NBLK - 1) && (tx == 15);   // j==2047 -> zero
    float4 acc0 = {0, 0, 0, 0}, acc1 = {0, 0, 0, 0};
    float4 acc2 = {0, 0, 0, 0}, acc3 = {0, 0, 0, 0};
    for (int k0 = 0; k0 < BR; k0 += 4) {
        int x = k0 >> 6;
        const float* Bb = K + (size_t)(x * 3 + ct) * PL +
                          (size_t)(s * 64 + (k0 & 63)) * NE + tgt0 + c0;
        float4 b0 = *(const float4*)(Bb);
        float4 b1 = *(const float4*)(Bb + NE);
        float4 b2 = *(const float4*)(Bb + 2 * NE);
        float4 b3 = *(const float4*)(Bb + 3 * NE);
        if (maskLast) { b0.w = 0.f; b1.w = 0.f; b2.w = 0.f; b3.w = 0.f; }
        float4 a0 = *(const float4*)(Ga + (size_t)(row0 + 0) * BR + k0);
        float4 a1 = *(const float4*)(Ga + (size_t)(row0 + 1) * BR + k0);
        float4 a2 = *(const float4*)(Ga + (size_t)(row0 + 2) * BR + k0);
        float4 a3 = *(const float4*)(Ga + (size_t)(row0 + 3) * BR + k0);
        FMA4(acc0, a0.x, b0); FMA4(acc0, a0.y, b1); FMA4(acc0, a0.z, b2); FMA4(acc0, a0.w, b3);
        FMA4(acc1, a1.x, b0); FMA4(acc1, a1.y, b1); FMA4(acc1, a1.z, b2); FMA4(acc1, a1.w, b3);
        FMA4(acc2, a2.x, b0); FMA4(acc2, a2.y, b1); FMA4(acc2, a2.z, b2); FMA4(acc2, a2.w, b3);
        FMA4(acc3, a3.x, b0); FMA4(acc3, a3.y, b1); FMA4(acc3, a3.z, b2); FMA4(acc3, a3.w, b3);
    }
    float* Ob = O + (size_t)row0 * BR + ct * 64 + c0;
    *(float4*)(Ob + 0 * BR) = acc0;
    *(float4*)(Ob + 1 * BR) = acc1;
    *(float4*)(Ob + 2 * BR) = acc2;
    *(float4*)(Ob + 3 * BR) = acc3;
}

// pr[m][w]: w=0: P = HwA@G_C; w=1: R2 = HwA@H_C + J2_A; w=2: R3 = HwA@J2_C + J3_A.
// HwA = H_A with k-col scaled by w(C*64+(k&63)). LDS-free. grid (16, 3, 9).
__global__ __launch_bounds__(256) void k_gops2(const float* __restrict__ E,
                                               const float* __restrict__ G,
                                               const float* __restrict__ ops1,
                                               float* __restrict__ pr) {
    int m = blockIdx.x, w = blockIdx.y, tz = blockIdx.z;
    int rt = tz / 3, ct = tz % 3;
    int A = 2 * m, C = 2 * m + 1;
    int tid = threadIdx.x;
    float dy = dy_of(E);
    const float* Asrc = ops1 + (size_t)(A * 3 + 0) * BR * BR;
    const float* Bsrc = (w == 0) ? (G + (size_t)C * BR * BR)
                                 : (ops1 + (size_t)(C * 3 + (w - 1)) * BR * BR);
    const float* Dsrc = (w == 0) ? nullptr : (ops1 + (size_t)(A * 3 + w) * BR * BR);
    float* O = pr + (size_t)(m * 3 + w) * BR * BR;
    int tx = tid & 15, ty = tid >> 4;
    int row0 = rt * 64 + ty * 4;
    int c0 = ct * 64 + tx * 4;
    float4 acc0 = {0, 0, 0, 0}, acc1 = {0, 0, 0, 0};
    float4 acc2 = {0, 0, 0, 0}, acc3 = {0, 0, 0, 0};
    for (int k0 = 0; k0 < BR; k0 += 4) {
        int e0 = C * 64 + (k0 & 63);
        float w0 = (e0 + 0 < NROWS) ? dy * E[e0 + 0] : 0.f;
        float w1 = (e0 + 1 < NROWS) ? dy * E[e0 + 1] : 0.f;
        float w2 = (e0 + 2 < NROWS) ? dy * E[e0 + 2] : 0.f;
        float w3 = (e0 + 3 < NROWS) ? dy * E[e0 + 3] : 0.f;
        const float* Bb = Bsrc + (size_t)k0 * BR + c0;
        float4 b0 = *(const float4*)(Bb + 0 * BR);
        float4 b1 = *(const float4*)(Bb + 1 * BR);
        float4 b2 = *(const float4*)(Bb + 2 * BR);
        float4 b3 = *(const float4*)(Bb + 3 * BR);
        b0.x *= w0; b0.y *= w0; b0.z *= w0; b0.w *= w0;
        b1.x *= w1; b1.y *= w1; b1.z *= w1; b1.w *= w1;
        b2.x *= w2; b2.y *= w2; b2.z *= w2; b2.w *= w2;
        b3.x *= w3; b3.y *= w3; b3.z *= w3; b3.w *= w3;
        float4 a0 = *(const float4*)(Asrc + (size_t)(row0 + 0) * BR + k0);
        float4 a1 = *(const float4*)(Asrc + (size_t)(row0 + 1) * BR + k0);
        float4 a2 = *(const float4*)(Asrc + (size_t)(row0 + 2) * BR + k0);
        float4 a3 = *(const float4*)(Asrc + (size_t)(row0 + 3) * BR + k0);
        FMA4(acc0, a0.x, b0); FMA4(acc0, a0.y, b1); FMA4(acc0, a0.z, b2); FMA4(acc0, a0.w, b3);
        FMA4(acc1, a1.x, b0); FMA4(acc1, a1.y, b1); FMA4(acc1, a1.z, b2); FMA4(acc1, a1.w, b3);
        FMA4(acc2, a2.x, b0); FMA4(acc2, a2.y, b1); FMA4(acc2, a2.z, b2); FMA4(acc2, a2.w, b3);
        FMA4(acc3, a3.x, b0); FMA4(acc3, a3.y, b1); FMA4(acc3, a3.z, b2); FMA4(acc3, a3.w, b3);
    }
    float* Ob = O + (size_t)row0 * BR + c0;
    if (Dsrc) {
        const float* Db = Dsrc + (size_t)row0 * BR + c0;
        float4 d0 = *(const float4*)(Db + 0 * BR);
        float4 d1 = *(const float4*)(Db + 1 * BR);
        float4 d2 = *(const float4*)(Db + 2 * BR);
        float4 d3 = *(const float4*)(Db + 3 * BR);
        acc0.x += d0.x; acc0.y += d0.y; acc0.z += d0.z; acc0.w += d0.w;
        acc1.x += d1.x; acc1.y += d1.y; acc1.z += d1.z; acc1.w += d1.w;
        acc2.x += d2.x; acc2.y += d2.y; acc2.z += d2.z; acc2.w += d2.w;
        acc3.x += d3.x; acc3.y += d3.y; acc3.z += d3.z; acc3.w += d3.w;
    }
    *(float4*)(Ob + 0 * BR) = acc0;
    *(float4*)(Ob + 1 * BR) = acc1;
    *(float4*)(Ob + 2 * BR) = acc2;
    *(float4*)(Ob + 3 * BR) = acc3;
}

// Pair stage (no intra-kernel deps):
//   bid 0..5 : F_C rows = G_C aC + H_C v2 + J2_C v3
//   bid 6..11: F_A rows = G_A aA + P aC + R2 v2 + R3 v3
//   bid >=12 : far — cols blocks 2m+2,2m+3 -> rows < 2m*64
__global__ __launch_bounds__(512) void k_pair2(const float* __restrict__ E,
                                               const float* __restrict__ K,
                                               const float* __restrict__ G,
                                               const float* __restrict__ ops1,
                                               const float* __restrict__ pr,
                                               float* __restrict__ acc,
                                               float* __restrict__ wf,
                                               float* __restrict__ out,
                                               int m, int hasV) {
    const size_t PL = (size_t)NE * NE;
    int A = 2 * m, C = 2 * m + 1;
    int tid = threadIdx.x;
    int bid = blockIdx.x;
    int lane = tid & 63, wv = tid >> 6;

    if (bid >= 12) {
        int jbase = (2 * m + 2) * BS;
        int row = (bid - 12) * 8 + wv;
        int j1 = jbase + lane, j2 = j1 + BS;
        float w10 = wf[0 * NE + j1], w11 = wf[1 * NE + j1], w12 = wf[2 * NE + j1];
        float w20 = 0.f, w21 = 0.f, w22 = 0.f;
        if (j2 < NROWS) {
            w20 = wf[0 * NE + j2]; w21 = wf[1 * NE + j2]; w22 = wf[2 * NE + j2];
        }
        const float* Kb1 = K + (size_t)row * NE + j1;
        const float* Kb2 = K + (size_t)row * NE + j2;
        float s0 = Kb1[0 * PL] * w10 + Kb1[1 * PL] * w11 + Kb1[2 * PL] * w12
                 + Kb2[0 * PL] * w20 + Kb2[1 * PL] * w21 + Kb2[2 * PL] * w22;
        float s1 = Kb1[3 * PL] * w10 + Kb1[4 * PL] * w11 + Kb1[5 * PL] * w12
                 + Kb2[3 * PL] * w20 + Kb2[4 * PL] * w21 + Kb2[5 * PL] * w22;
        float s2 = Kb1[6 * PL] * w10 + Kb1[7 * PL] * w11 + Kb1[8 * PL] * w12
                 + Kb2[6 * PL] * w20 + Kb2[7 * PL] * w21 + Kb2[8 * PL] * w22;
#pragma unroll
        for (int d = 32; d; d >>= 1) {
            s0 += __shfl_xor(s0, d);
            s1 += __shfl_xor(s1, d);
            s2 += __shfl_xor(s2, d);
        }
        if (lane == 0) {
            atomicAdd(&acc[0 * NE + row], s0);
            atomicAdd(&acc[1 * NE + row], s1);
            atomicAdd(&acc[2 * NE + row], s2);
        }
        return;
    }

    // ---- apply (planar vectors: idx = species*64 + energy) ----
    __shared__ float4 vec4[4][BR / 4];        // aC, aA, v2, v3
    float dy = dy_of(E);
    if (tid < BR) {
        int sp = tid >> 6, e = tid & 63;
        ((float*)vec4[0])[tid] = __hip_atomic_load(&acc[sp * NE + C * BS + e],
                                     __ATOMIC_RELAXED, __HIP_MEMORY_SCOPE_AGENT);
        ((float*)vec4[1])[tid] = __hip_atomic_load(&acc[sp * NE + A * BS + e],
                                     __ATOMIC_RELAXED, __HIP_MEMORY_SCOPE_AGENT);
        ((float*)vec4[2])[tid] = hasV ? wf[sp * NE + (2 * m + 2) * BS + e] : 0.f;
        ((float*)vec4[3])[tid] = hasV ? wf[sp * NE + (2 * m + 3) * BS + e] : 0.f;
    }
    __syncthreads();

    int rloc = tid >> 4, sub = tid & 15;      // 32 rows x 16 threads
    bool isC = (bid < 6);
    int rbase = (isC ? bid : bid - 6) * 32;
    int row = rbase + rloc;                   // planar row in [0,192)
    int blk = isC ? C : A;

    const float4* m0 = (const float4*)(G + ((size_t)blk * BR + row) * BR) + sub * 3;
    const float4 *m1, *m2, *m3 = nullptr;
    const float4 *x0, *x1, *x2, *x3 = nullptr;
    if (isC) {
        m1 = (const float4*)(ops1 + ((size_t)(C * 3 + 0) * BR + row) * BR) + sub * 3;
        m2 = (const float4*)(ops1 + ((size_t)(C * 3 + 1) * BR + row) * BR) + sub * 3;
        x0 = vec4[0] + sub * 3; x1 = vec4[2] + sub * 3; x2 = vec4[3] + sub * 3;
    } else {
        m1 = (const float4*)(pr + ((size_t)(m * 3 + 0) * BR + row) * BR) + sub * 3;
        m2 = (const float4*)(pr + ((size_t)(m * 3 + 1) * BR + row) * BR) + sub * 3;
        m3 = (const float4*)(pr + ((size_t)(m * 3 + 2) * BR + row) * BR) + sub * 3;
        x0 = vec4[1] + sub * 3; x1 = vec4[0] + sub * 3;
        x2 = vec4[2] + sub * 3; x3 = vec4[3] + sub * 3;
    }
    float s = 0.f;
#pragma unroll
    for (int q = 0; q < 3; ++q) s += DOT4(m0[q], x0[q]);
    if (hasV || !isC) {
#pragma unroll
        for (int q = 0; q < 3; ++q) s += DOT4(m1[q], x1[q]);
    }
    if (hasV) {
#pragma unroll
        for (int q = 0; q < 3; ++q) s += DOT4(m2[q], x2[q]);
        if (!isC) {
#pragma unroll
            for (int q = 0; q < 3; ++q) s += DOT4(m3[q], x3[q]);
        }
    }
    s += __shfl_xor(s, 1); s += __shfl_xor(s, 2);
    s += __shfl_xor(s, 4); s += __shfl_xor(s, 8);
    if (sub == 0) {
        int x = row >> 6, ii = row & 63;
        int i = blk * BS + ii;
        if (i < NROWS) {
            out[(1 + x) * NE + i] = s > 0.f ? s : 0.f;
            wf[x * NE + i] = dy * E[i] * s;
        }
    }
}

extern "C" void kernel_launch(void* const* d_in, const int* in_sizes, int n_in,
                              void* d_out, int out_size, void* d_ws, size_t ws_size,
                              hipStream_t stream) {
    const float* E = (const float*)d_in[0];
    const float* R = (const float*)d_in[1];
    const float* K = (const float*)d_in[2];
    const float* S0 = (const float*)d_in[3];
    const float* SC = (const float*)d_in[4];
    float* out = (float*)d_out;
    float* wf = (float*)d_ws;
    float* acc = wf + NX * NE;
    float* G = acc + NX * NE;
    float* ops1 = G + (size_t)NBLK * BR * BR;
    float* pr = ops1 + (size_t)NBLK * 3 * BR * BR;

    k_init<<<(NE + 255) / 256, 256, 0, stream>>>(E, R, K, S0, SC, out, wf, acc);
    k_tinv<<<dim3(NBLK, 3), TTH, 0, stream>>>(E, R, K, G);
    k_gops1<<<dim3(NBLK, 3, 9), 256, 0, stream>>>(K, G, ops1);
    k_gops2<<<dim3(NPAIR, 3, 9), 256, 0, stream>>>(E, G, ops1, pr);

    for (int m = NPAIR - 1; m >= 0; --m) {
        int nFar = (m < NPAIR - 1) ? m * 16 : 0;
        int hasV = (m < NPAIR - 1) ? 1 : 0;
        k_pair2<<<12 + nFar, 512, 0, stream>>>(E, K, G, ops1, pr, acc, wf, out,
                                               m, hasV);
    }
}